// Round 9
// baseline (459.077 us; speedup 1.0000x reference)
//
#include <hip/hip_runtime.h>
#include <hip/hip_bf16.h>

constexpr int C_B   = 64;
constexpr int C_NPG = 512;
constexpr int C_N   = 32768;
constexpr int C_E   = 524288;
constexpr int C_L   = 16;
constexpr int C_H   = 256;
constexpr int C_P   = 128;
constexpr int C_K1  = 256;
constexpr int C_K2  = 128;
constexpr int C_V   = 50000;

typedef __attribute__((ext_vector_type(8)))  short  short8;
typedef __attribute__((ext_vector_type(16))) float  float16;
typedef unsigned short ushort;
typedef unsigned int   uint;

__device__ inline void split_bf16(float x, ushort& h, ushort& l) {
    __hip_bfloat16 bh = __float2bfloat16(x);
    float fh = __bfloat162float(bh);
    __hip_bfloat16 bl = __float2bfloat16(x - fh);
    h = __builtin_bit_cast(ushort, bh);
    l = __builtin_bit_cast(ushort, bl);
}

__device__ inline ushort f2h(float x) {
    return __builtin_bit_cast(ushort, (_Float16)x);
}
__device__ inline float h2f(ushort x) {
    return (float)__builtin_bit_cast(_Float16, x);
}
__device__ inline float4 h4_to_f4(ushort4 v) {
    return make_float4(h2f(v.x), h2f(v.y), h2f(v.z), h2f(v.w));
}

// hybrid bitonic sort, descending
template <int NPER>
__device__ inline void bitonic_desc(float& v, int& idx, float* svL, int* siL, int t) {
    #pragma unroll
    for (int k = 2; k <= NPER; k <<= 1) {
        bool desc = ((t & k) == 0);
        #pragma unroll
        for (int j = k >> 1; j > 0; j >>= 1) {
            bool amLo = ((t & j) == 0);
            bool keepMax = (desc == amLo);
            float pv; int pi;
            if (j >= 64) {
                __syncthreads();
                svL[t] = v; siL[t] = idx;
                __syncthreads();
                pv = svL[t ^ j]; pi = siL[t ^ j];
            } else {
                pv = __shfl_xor(v, j, 64);
                pi = __shfl_xor(idx, j, 64);
            }
            bool take = keepMax ? (pv > v) : (pv < v);
            if (take) { v = pv; idx = pi; }
        }
    }
}

// ---------------- fused preprocessing: embcvt | edge_w | wprep | p-norms -----
__global__ void k_pre(const float* __restrict__ emb, ushort* __restrict__ emb16,
                      const float* __restrict__ ea, const int* __restrict__ dst,
                      float* __restrict__ w, float* __restrict__ degb, int* __restrict__ indegb,
                      const float* __restrict__ W0, const float* __restrict__ W1,
                      ushort* __restrict__ W0h, ushort* __restrict__ W0l,
                      ushort* __restrict__ W1h, ushort* __restrict__ W1l,
                      const float* __restrict__ p0, const float* __restrict__ p1,
                      float* __restrict__ invnp) {
    int b = blockIdx.x, t = threadIdx.x;
    __shared__ float r[256];
    if (b < 6250) {
        int i = (b * 256 + t) * 8;
        float4 a = *(const float4*)&emb[i];
        float4 c = *(const float4*)&emb[i + 4];
        short8 o;
        o[0] = (short)f2h(a.x); o[1] = (short)f2h(a.y);
        o[2] = (short)f2h(a.z); o[3] = (short)f2h(a.w);
        o[4] = (short)f2h(c.x); o[5] = (short)f2h(c.y);
        o[6] = (short)f2h(c.z); o[7] = (short)f2h(c.w);
        *(short8*)&emb16[i] = o;
    } else if (b < 8298) {
        int e = (b - 6250) * 256 + t;
        float ww = 0.5f * (ea[2 * e] + ea[2 * e + 1]);
        w[e] = ww;
        int d = dst[e];
        atomicAdd(&degb[d], ww);
        atomicAdd(&indegb[d], 1);
    } else if (b < 8810) {
        int g = (b - 8298) * 256 + t;
        int which = g >> 16;
        int idx = g & 65535;
        int k = idx >> 8, n = idx & 255;
        float x = (which ? W1 : W0)[idx];
        ushort h, l;
        split_bf16(x, h, l);
        size_t a = ((size_t)(n >> 5) * 16 + (k >> 4)) * 512 + ((k >> 3) & 1) * 256
                 + (n & 31) * 8 + (k & 7);
        if (which) { W1h[a] = h; W1l[a] = l; }
        else       { W0h[a] = h; W0l[a] = l; }
    } else {
        const float* p = (b == 8810) ? p0 : p1;
        float v = p[t];
        r[t] = v * v; __syncthreads();
        for (int s = 128; s; s >>= 1) { if (t < s) r[t] += r[t + s]; __syncthreads(); }
        if (t == 0) invnp[b - 8810] = rsqrtf(r[0]);
    }
}

// ---------------- ST encoder (16 rows/block) + layer-1 scan (merged) ---------
__global__ __launch_bounds__(256)
void k_st_scan(const int* __restrict__ tokens, const ushort* __restrict__ emb16,
               ushort* __restrict__ Xh, ushort* __restrict__ Xl,
               const int* __restrict__ indeg, int* __restrict__ rowstart,
               int* __restrict__ cursor, float* __restrict__ deg,
               float* __restrict__ dinv) {
    __shared__ float Xs[16 * 257];
    __shared__ int tokS[256];
    int blk = blockIdx.x, t = threadIdx.x;
    if (blk < 2048) {                       // st_encode: 16 nodes per block
        tokS[t] = tokens[(size_t)blk * 256 + t];
        __syncthreads();
        int w = t >> 6, lane = t & 63;
        #pragma unroll
        for (int i = 0; i < 4; ++i) {
            int nl = w * 4 + i;
            float4 acc = make_float4(0.f, 0.f, 0.f, 0.f);
            int cnt = 0;
            #pragma unroll
            for (int tt = 0; tt < C_L; ++tt) {
                int tk = tokS[nl * 16 + tt];          // wave-uniform
                if (tk != 0) {
                    float4 ev = h4_to_f4(*(const ushort4*)&emb16[(size_t)tk * C_H + lane * 4]);
                    acc.x += ev.x; acc.y += ev.y; acc.z += ev.z; acc.w += ev.w;
                    cnt++;
                }
            }
            float inv = 1.f / fmaxf((float)cnt, 1.f);
            float* xr = &Xs[nl * 257 + lane * 4];
            xr[0] = acc.x * inv; xr[1] = acc.y * inv;
            xr[2] = acc.z * inv; xr[3] = acc.w * inv;
        }
        __syncthreads();
        int mtile = blk >> 1, rlo = (blk & 1) * 16;
        #pragma unroll
        for (int i = 0; i < 2; ++i) {
            int u = t + 256 * i;                      // [0,512)
            int kst = u >> 5, rr = u & 15, khalf = (u >> 4) & 1;
            int kb = kst * 16 + khalf * 8;
            int ln = khalf * 32 + rlo + rr;
            short8 hv, lv;
            #pragma unroll
            for (int j = 0; j < 8; ++j) {
                ushort h, l;
                split_bf16(Xs[rr * 257 + kb + j], h, l);
                hv[j] = (short)h; lv[j] = (short)l;
            }
            size_t base = (size_t)mtile * 8192 + ((size_t)kst * 64 + ln) * 8;
            *(short8*)&Xh[base] = hv;
            *(short8*)&Xl[base] = lv;
        }
    } else {                                // scan: one wave per graph
        int g = blk - 2048;
        if (t < 64) {
            int lane = t;
            int nodebase = g * C_NPG + lane * 8;
            int a[8];
            int tot = 0;
            #pragma unroll
            for (int i = 0; i < 8; ++i) { a[i] = indeg[nodebase + i]; tot += a[i]; }
            int sc = tot;
            #pragma unroll
            for (int off = 1; off < 64; off <<= 1) {
                int pv = __shfl_up(sc, off, 64);
                if (lane >= off) sc += pv;
            }
            int run = g * 8192 + sc - tot;
            #pragma unroll
            for (int i = 0; i < 8; ++i) {
                rowstart[nodebase + i] = run;
                cursor[nodebase + i]   = run;
                run += a[i];
                float d = deg[nodebase + i] + 1.f;
                dinv[nodebase + i] = rsqrtf(d);
                deg[nodebase + i]  = 1.f / d;         // selfw
            }
        }
    }
}

// ---------------- GEMM body (split-bf16 3-term MFMA, fp16 out) ---------------
__device__ inline void gemm_body(const ushort* __restrict__ Ah, const ushort* __restrict__ Al,
                                 const ushort* __restrict__ Bh, const ushort* __restrict__ Bl,
                                 ushort* __restrict__ C, int mb, int nb, int tid) {
    __shared__ short lds[16384];
    int lane = tid & 63;
    int wid  = tid >> 6;
    int wm   = wid & 1, wn = wid >> 1;
    float16 acc[2][2];
    #pragma unroll
    for (int mi = 0; mi < 2; ++mi)
        #pragma unroll
        for (int ni = 0; ni < 2; ++ni)
            #pragma unroll
            for (int r = 0; r < 16; ++r) acc[mi][ni][r] = 0.f;
    for (int kc = 0; kc < 8; ++kc) {
        __syncthreads();
        #pragma unroll
        for (int i = 0; i < 4; ++i) {
            int a  = tid + 256 * i;
            int s  = a >> 9;
            int mt = (a >> 7) & 3;
            int k2 = (a >> 6) & 1;
            int ln = a & 63;
            const ushort* ap = (s ? Al : Ah)
                + (((size_t)(mb * 4 + mt) * 16 + kc * 2 + k2) * 64 + ln) * 8;
            *(int4*)&lds[a * 8] = *(const int4*)ap;
            const ushort* bp = (s ? Bl : Bh)
                + (((size_t)(nb * 4 + mt) * 16 + kc * 2 + k2) * 64 + ln) * 8;
            *(int4*)&lds[8192 + a * 8] = *(const int4*)bp;
        }
        __syncthreads();
        #pragma unroll
        for (int k2 = 0; k2 < 2; ++k2) {
            short8 ah[2], al[2], bh[2], bl[2];
            #pragma unroll
            for (int mi = 0; mi < 2; ++mi) {
                int mt = wm * 2 + mi;
                ah[mi] = *(short8*)&lds[((mt * 2 + k2) * 64 + lane) * 8];
                al[mi] = *(short8*)&lds[(((4 + mt) * 2 + k2) * 64 + lane) * 8];
            }
            #pragma unroll
            for (int ni = 0; ni < 2; ++ni) {
                int nt = wn * 2 + ni;
                bh[ni] = *(short8*)&lds[8192 + ((nt * 2 + k2) * 64 + lane) * 8];
                bl[ni] = *(short8*)&lds[8192 + (((4 + nt) * 2 + k2) * 64 + lane) * 8];
            }
            #pragma unroll
            for (int mi = 0; mi < 2; ++mi)
                #pragma unroll
                for (int ni = 0; ni < 2; ++ni) {
                    acc[mi][ni] = __builtin_amdgcn_mfma_f32_32x32x16_bf16(
                        ah[mi], bh[ni], acc[mi][ni], 0, 0, 0);
                    acc[mi][ni] = __builtin_amdgcn_mfma_f32_32x32x16_bf16(
                        ah[mi], bl[ni], acc[mi][ni], 0, 0, 0);
                    acc[mi][ni] = __builtin_amdgcn_mfma_f32_32x32x16_bf16(
                        al[mi], bh[ni], acc[mi][ni], 0, 0, 0);
                }
        }
    }
    int col = lane & 31;
    int rquad = 4 * (lane >> 5);
    #pragma unroll
    for (int mi = 0; mi < 2; ++mi)
        #pragma unroll
        for (int ni = 0; ni < 2; ++ni) {
            int mbase = mb * 128 + wm * 64 + mi * 32;
            int nbase = nb * 128 + wn * 64 + ni * 32 + col;
            #pragma unroll
            for (int r = 0; r < 16; ++r) {
                int row = (r & 3) + 8 * (r >> 2) + rquad;
                C[(size_t)(mbase + row) * C_H + nbase] = f2h(acc[mi][ni][r]);
            }
        }
}

// ---------------- GEMM-1 + layer-1 CSR build (merged launch) -----------------
__global__ __launch_bounds__(256)
void k_gemm1_csr(const ushort* __restrict__ Ah, const ushort* __restrict__ Al,
                 const ushort* __restrict__ Bh, const ushort* __restrict__ Bl,
                 ushort* __restrict__ C,
                 const int* __restrict__ src, const int* __restrict__ dst,
                 const float* __restrict__ wv, const float* __restrict__ dinv,
                 int* __restrict__ cursor, int* __restrict__ csr_src,
                 float* __restrict__ csr_nrm) {
    int b = blockIdx.x, t = threadIdx.x;
    if (b < 512) {
        gemm_body(Ah, Al, Bh, Bl, C, b & 255, b >> 8, t);
    } else {
        int e = (b - 512) * 256 + t;
        int s = src[e], d = dst[e];
        int slot = atomicAdd(&cursor[d], 1);
        csr_src[slot] = s;
        csr_nrm[slot] = dinv[s] * wv[e] * dinv[d];
    }
}

// ---------------- GEMM-2 (standalone) ----------------
__global__ __launch_bounds__(256)
void k_gemm_mfma(const ushort* __restrict__ Ah, const ushort* __restrict__ Al,
                 const ushort* __restrict__ Bh, const ushort* __restrict__ Bl,
                 ushort* __restrict__ C) {
    gemm_body(Ah, Al, Bh, Bl, C, blockIdx.x, blockIdx.y, threadIdx.x);
}

// ---------------- layer-1 GCN aggregate: LDS-resident H quarter --------------
__global__ __launch_bounds__(512)
void k_gcn_lds1(const ushort* __restrict__ Hhf, const int* __restrict__ rowst,
                const int* __restrict__ indeg, const int* __restrict__ csrs,
                const float* __restrict__ csrn, const float* __restrict__ selfw,
                const float* __restrict__ bias, const float* __restrict__ p,
                float* __restrict__ Xout, float* __restrict__ scoreQ) {
    __shared__ ushort Hs[C_NPG * 64];       // 64 KB
    int q = blockIdx.x, g = blockIdx.y, t = threadIdx.x;
    int lane = t & 63, w = t >> 6;
    #pragma unroll
    for (int i = 0; i < 8; ++i) {
        int u = t + 512 * i;                // [0,4096) 16B units
        int r = u >> 3, uu = u & 7;
        *(short8*)&Hs[r * 64 + uu * 8] =
            *(const short8*)&Hhf[(size_t)(g * C_NPG + r) * C_H + q * 64 + uu * 8];
    }
    __syncthreads();
    float bq = bias[q * 64 + lane];
    float pq = p[q * 64 + lane];
    for (int i = 0; i < 64; ++i) {
        int nl = w * 64 + i;
        int n  = g * C_NPG + nl;
        float sw = selfw[n];
        float acc = fmaf(h2f(Hs[nl * 64 + lane]), sw, bq);
        int start = rowst[n], cnt = indeg[n];
        #pragma unroll 4
        for (int j = 0; j < cnt; ++j) {
            int   s  = csrs[start + j] - g * C_NPG;
            float nm = csrn[start + j];
            acc = fmaf(nm, h2f(Hs[s * 64 + lane]), acc);
        }
        acc = fmaxf(acc, 0.f);
        Xout[(size_t)n * C_H + q * 64 + lane] = acc;
        float sc = acc * pq;
        #pragma unroll
        for (int m = 32; m; m >>= 1) sc += __shfl_xor(sc, m, 64);
        if (lane == 0) scoreQ[q * C_N + n] = sc;
    }
}

// ---------------- layer-2 GCN aggregate: LDS-resident H half -----------------
__global__ __launch_bounds__(512)
void k_gcn_lds2(const ushort* __restrict__ Hhf, const int* __restrict__ rowst1,
                const int* __restrict__ indeg1, const int* __restrict__ csrs,
                const float* __restrict__ csrn, const float* __restrict__ selfw1,
                const float* __restrict__ bias, const float* __restrict__ p,
                ushort* __restrict__ Xtmp, float* __restrict__ scoreQ) {
    __shared__ ushort Hs[C_K1 * 128];       // 64 KB
    int h = blockIdx.x, g = blockIdx.y, t = threadIdx.x;
    int lane = t & 63, w = t >> 6;
    #pragma unroll
    for (int i = 0; i < 8; ++i) {
        int u = t + 512 * i;                // [0,4096) 16B units
        int r = u >> 4, uu = u & 15;
        *(short8*)&Hs[r * 128 + uu * 8] =
            *(const short8*)&Hhf[(size_t)(g * C_K1 + r) * C_H + h * 128 + uu * 8];
    }
    __syncthreads();
    float2 bq = *(const float2*)&bias[h * 128 + lane * 2];
    float2 pq = *(const float2*)&p[h * 128 + lane * 2];
    for (int i = 0; i < 32; ++i) {
        int nl = w * 32 + i;
        int n  = g * C_K1 + nl;
        float sw = selfw1[n];
        ushort2 hv = *(const ushort2*)&Hs[nl * 128 + lane * 2];
        float ax = fmaf(h2f(hv.x), sw, bq.x);
        float ay = fmaf(h2f(hv.y), sw, bq.y);
        int start = rowst1[n], cnt = indeg1[n];
        #pragma unroll 4
        for (int j = 0; j < cnt; ++j) {
            int   s  = csrs[start + j] - g * C_K1;
            float nm = csrn[start + j];
            ushort2 xv = *(const ushort2*)&Hs[s * 128 + lane * 2];
            ax = fmaf(nm, h2f(xv.x), ax);
            ay = fmaf(nm, h2f(xv.y), ay);
        }
        ax = fmaxf(ax, 0.f); ay = fmaxf(ay, 0.f);
        ushort2 o; o.x = f2h(ax); o.y = f2h(ay);
        *(ushort2*)&Xtmp[(size_t)n * C_H + h * 128 + lane * 2] = o;
        float sc = ax * pq.x + ay * pq.y;
        #pragma unroll
        for (int m = 32; m; m >>= 1) sc += __shfl_xor(sc, m, 64);
        if (lane == 0) scoreQ[h * C_N + n] = sc;
    }
}

// ---------------- fused pool-1: sort + attpool-1 + frag emit + layer-2 prep --
__global__ __launch_bounds__(512)
void k_pool1_fused(const float* __restrict__ scoreQ, const float* __restrict__ invnp,
                   const float* __restrict__ X,
                   const int* __restrict__ src, const int* __restrict__ dst,
                   const float* __restrict__ wbuf,
                   const float* __restrict__ wg, const float* __restrict__ bg,
                   ushort* __restrict__ XFh, ushort* __restrict__ XFl,
                   float* __restrict__ outb,
                   float* __restrict__ selfw1, int* __restrict__ rowst1,
                   int* __restrict__ indeg1, int* __restrict__ csrs,
                   float* __restrict__ csrn) {
    int g = blockIdx.x, t = threadIdx.x;
    int lane = t & 63, w = t >> 6;
    __shared__ float svL[C_NPG];
    __shared__ int   siL[C_NPG];
    __shared__ int   nooL[C_NPG];
    __shared__ int   olds[C_K1];
    __shared__ float gt[C_K1];
    __shared__ float sd[C_K1];
    __shared__ float red[C_K1];
    __shared__ float an[C_K1];
    __shared__ float wsum[8][C_H];
    __shared__ int   indegL[C_K1];
    __shared__ float degL[C_K1];
    __shared__ float dinvL[C_K1];
    __shared__ int   cursL[C_K1];

    int t0 = g * C_NPG + t;
    float v = (scoreQ[t0] + scoreQ[C_N + t0] + scoreQ[2 * C_N + t0] + scoreQ[3 * C_N + t0])
              * invnp[0];
    int idx = t;
    bitonic_desc<C_NPG>(v, idx, svL, siL, t);
    __syncthreads();
    nooL[idx] = (t < C_K1) ? t : -1;
    if (t < C_K1) {
        olds[t]   = idx;
        gt[t]     = tanhf(v);
        indegL[t] = 0;
        degL[t]   = 0.f;
    }
    __syncthreads();

    float bgv = bg[0];
    {
        int r = t >> 1, half = t & 1;
        const float* xr = &X[(size_t)(g * C_NPG + olds[r]) * C_H + half * 128];
        const float* wr = &wg[half * 128];
        float s = 0.f;
        #pragma unroll
        for (int kk = 0; kk < 128; kk += 4) {
            float4 xv = *(const float4*)&xr[kk];
            float4 wv = *(const float4*)&wr[kk];
            s += xv.x * wv.x + xv.y * wv.y + xv.z * wv.z + xv.w * wv.w;
        }
        if (half) red[r] = s;
        __syncthreads();
        if (!half) sd[r] = gt[r] * (s + red[r]) + bgv;
        __syncthreads();
    }
    if (w == 0) {
        float m = fmaxf(fmaxf(sd[lane], sd[lane + 64]), fmaxf(sd[lane + 128], sd[lane + 192]));
        #pragma unroll
        for (int mm = 32; mm; mm >>= 1) m = fmaxf(m, __shfl_xor(m, mm, 64));
        if (lane == 0) red[0] = m;
    }
    __syncthreads();
    float mx = red[0];
    if (t < C_K1) an[t] = expf(sd[t] - mx);
    __syncthreads();
    if (w == 0) {
        float s4 = an[lane] + an[lane + 64] + an[lane + 128] + an[lane + 192];
        #pragma unroll
        for (int mm = 32; mm; mm >>= 1) s4 += __shfl_xor(s4, mm, 64);
        if (lane == 0) red[1] = s4;
    }
    __syncthreads();
    if (t < C_K1) an[t] = an[t] / red[1] * gt[t];
    __syncthreads();
    {
        float4 a4 = make_float4(0.f, 0.f, 0.f, 0.f);
        #pragma unroll 4
        for (int r = 0; r < 32; ++r) {
            int rr = w * 32 + r;
            float a = an[rr];
            float4 xv = *(const float4*)&X[(size_t)(g * C_NPG + olds[rr]) * C_H + lane * 4];
            a4.x = fmaf(a, xv.x, a4.x); a4.y = fmaf(a, xv.y, a4.y);
            a4.z = fmaf(a, xv.z, a4.z); a4.w = fmaf(a, xv.w, a4.w);
        }
        *(float4*)&wsum[w][lane * 4] = a4;
        __syncthreads();
        if (t < C_H) {
            float s = wsum[0][t] + wsum[1][t] + wsum[2][t] + wsum[3][t]
                    + wsum[4][t] + wsum[5][t] + wsum[6][t] + wsum[7][t];
            outb[g * C_H + t] = s;
        }
    }

    // frag emission for GEMM-2 directly from global X
    #pragma unroll
    for (int i = 0; i < 16; ++i) {
        int u   = t + 512 * i;
        int mt  = u >> 10;
        int c   = u & 1023;
        int kst = c >> 6, ln = c & 63, ml = ln & 31;
        int kb  = kst * 16 + (ln >> 5) * 8;
        int r   = mt * 32 + ml;
        const float* xp = &X[(size_t)(g * C_NPG + olds[r]) * C_H + kb];
        float gg = gt[r];
        float4 a = *(const float4*)&xp[0];
        float4 b = *(const float4*)&xp[4];
        float e8[8] = {a.x * gg, a.y * gg, a.z * gg, a.w * gg,
                       b.x * gg, b.y * gg, b.z * gg, b.w * gg};
        short8 hv, lv;
        #pragma unroll
        for (int j = 0; j < 8; ++j) {
            ushort h, l;
            split_bf16(e8[j], h, l);
            hv[j] = (short)h; lv[j] = (short)l;
        }
        size_t base = (size_t)(g * 8 + mt) * 8192 + (size_t)c * 8;
        *(short8*)&XFh[base] = hv;
        *(short8*)&XFl[base] = lv;
    }

    // layer-2 graph prep
    int   nsR[16], ndR[16];
    float wwR[16];
    #pragma unroll
    for (int i = 0; i < 16; ++i) {
        int e  = g * 8192 + t + 512 * i;
        int ns = nooL[src[e] - g * C_NPG];
        int nd = nooL[dst[e] - g * C_NPG];
        float ww = wbuf[e];
        nsR[i] = ns; ndR[i] = nd; wwR[i] = ww;
        if (ns >= 0 && nd >= 0) {
            atomicAdd(&indegL[nd], 1);
            unsafeAtomicAdd(&degL[nd], ww);
        }
    }
    __syncthreads();
    if (t < C_K1) {
        float d = degL[t] + 1.f;
        dinvL[t] = rsqrtf(d);
        selfw1[g * C_K1 + t] = 1.f / d;
        indeg1[g * C_K1 + t] = indegL[t];
    }
    if (w == 0) {
        int a0 = indegL[lane * 4], a1 = indegL[lane * 4 + 1];
        int a2 = indegL[lane * 4 + 2], a3 = indegL[lane * 4 + 3];
        int s4 = a0 + a1 + a2 + a3;
        int sc = s4;
        #pragma unroll
        for (int off = 1; off < 64; off <<= 1) {
            int pv = __shfl_up(sc, off, 64);
            if (lane >= off) sc += pv;
        }
        int base = g * 8192 + (sc - s4);
        cursL[lane * 4]     = base;
        cursL[lane * 4 + 1] = base + a0;
        cursL[lane * 4 + 2] = base + a0 + a1;
        cursL[lane * 4 + 3] = base + a0 + a1 + a2;
        rowst1[g * C_K1 + lane * 4]     = base;
        rowst1[g * C_K1 + lane * 4 + 1] = base + a0;
        rowst1[g * C_K1 + lane * 4 + 2] = base + a0 + a1;
        rowst1[g * C_K1 + lane * 4 + 3] = base + a0 + a1 + a2;
    }
    __syncthreads();
    #pragma unroll
    for (int i = 0; i < 16; ++i) {
        int ns = nsR[i], nd = ndR[i];
        if (ns >= 0 && nd >= 0) {
            int slot = atomicAdd(&cursL[nd], 1);
            csrs[slot] = g * C_K1 + ns;
            csrn[slot] = dinvL[ns] * wwR[i] * dinvL[nd];
        }
    }
}

// ---------------- fused pool-2 + attpool-2 + projection head -----------------
__global__ __launch_bounds__(256)
void k_pool2_head(const float* __restrict__ scoreQ, const float* __restrict__ invnp,
                  const ushort* __restrict__ Xtmp,
                  const float* __restrict__ wg, const float* __restrict__ bg,
                  const float* __restrict__ outb,
                  const float* __restrict__ Wp1, const float* __restrict__ bp1,
                  const float* __restrict__ Wp2, const float* __restrict__ bp2,
                  float* __restrict__ dout) {
    int g = blockIdx.x, t = threadIdx.x;
    int lane = t & 63, w = t >> 6;
    __shared__ float svL[C_K1];
    __shared__ int   siL[C_K1];
    __shared__ int   olds[C_K2];
    __shared__ float gt[C_K2];
    __shared__ float sd[C_K2];
    __shared__ float red2[C_K2];
    __shared__ float an[C_K2];
    __shared__ float wsum[4][C_H];
    __shared__ float so[C_H];

    int n0 = g * C_K1 + t;
    float v = (scoreQ[n0] + scoreQ[C_N + n0]) * invnp[1];
    int idx = t;
    bitonic_desc<C_K1>(v, idx, svL, siL, t);
    __syncthreads();
    if (t < C_K2) { olds[t] = idx; gt[t] = tanhf(v); }
    __syncthreads();

    float bgv = bg[0];
    {
        int r = t >> 1, half = t & 1;
        const ushort* xr = &Xtmp[(size_t)(g * C_K1 + olds[r]) * C_H + half * 128];
        const float* wr = &wg[half * 128];
        float s = 0.f;
        #pragma unroll
        for (int kk = 0; kk < 128; kk += 4) {
            float4 xv = h4_to_f4(*(const ushort4*)&xr[kk]);
            float4 wv = *(const float4*)&wr[kk];
            s += xv.x * wv.x + xv.y * wv.y + xv.z * wv.z + xv.w * wv.w;
        }
        if (half) red2[r] = s;
        __syncthreads();
        if (!half) sd[r] = gt[r] * (s + red2[r]) + bgv;
        __syncthreads();
    }
    if (w == 0) {
        float m = fmaxf(sd[lane], sd[lane + 64]);
        #pragma unroll
        for (int mm = 32; mm; mm >>= 1) m = fmaxf(m, __shfl_xor(m, mm, 64));
        if (lane == 0) red2[0] = m;
    }
    __syncthreads();
    float mx = red2[0];
    if (t < C_K2) an[t] = expf(sd[t] - mx);
    __syncthreads();
    if (w == 0) {
        float s2 = an[lane] + an[lane + 64];
        #pragma unroll
        for (int mm = 32; mm; mm >>= 1) s2 += __shfl_xor(s2, mm, 64);
        if (lane == 0) red2[1] = s2;
    }
    __syncthreads();
    if (t < C_K2) an[t] = an[t] / red2[1] * gt[t];
    __syncthreads();
    {
        float4 a4 = make_float4(0.f, 0.f, 0.f, 0.f);
        #pragma unroll 4
        for (int r = 0; r < 32; ++r) {
            int rr = w * 32 + r;
            float a = an[rr];
            float4 xv = h4_to_f4(*(const ushort4*)&Xtmp[(size_t)(g * C_K1 + olds[rr]) * C_H + lane * 4]);
            a4.x = fmaf(a, xv.x, a4.x); a4.y = fmaf(a, xv.y, a4.y);
            a4.z = fmaf(a, xv.z, a4.z); a4.w = fmaf(a, xv.w, a4.w);
        }
        *(float4*)&wsum[w][lane * 4] = a4;
    }
    __syncthreads();
    float o = outb[g * C_H + t] + wsum[0][t] + wsum[1][t] + wsum[2][t] + wsum[3][t];
    so[t] = o;
    dout[C_B * C_P + g * C_H + t] = o;      // second output
    __syncthreads();

    // projection head
    float lg = 0.f;
    if (t < C_P) {
        float acc = bp1[t];
        for (int k = 0; k < C_H; ++k) acc += so[k] * Wp1[k * C_P + t];
        float hv = fmaxf(acc, 0.f);
        an[t] = hv;                          // reuse as sh
    }
    __syncthreads();
    if (t < C_P) {
        lg = bp2[t];
        for (int k = 0; k < C_P; ++k) lg += an[k] * Wp2[k * C_P + t];
        red2[t] = lg * lg;
    }
    __syncthreads();
    for (int s = 64; s; s >>= 1) { if (t < s) red2[t] += red2[t + s]; __syncthreads(); }
    float nrm = fmaxf(sqrtf(red2[0]), 1e-12f);
    if (t < C_P) dout[g * C_P + t] = lg / nrm;
}

extern "C" void kernel_launch(void* const* d_in, const int* in_sizes, int n_in,
                              void* d_out, int out_size, void* d_ws, size_t ws_size,
                              hipStream_t stream) {
    const int*   tokens = (const int*)d_in[0];
    const int*   src    = (const int*)d_in[1];
    const int*   dst    = (const int*)d_in[2];
    const float* eattr  = (const float*)d_in[3];
    const float* emb    = (const float*)d_in[4];
    const float* W0     = (const float*)d_in[5];
    const float* b0     = (const float*)d_in[6];
    const float* W1     = (const float*)d_in[7];
    const float* b1     = (const float*)d_in[8];
    const float* p0     = (const float*)d_in[9];
    const float* p1     = (const float*)d_in[10];
    const float* wg     = (const float*)d_in[11];
    const float* bg     = (const float*)d_in[12];
    const float* Wp1    = (const float*)d_in[13];
    const float* bp1    = (const float*)d_in[14];
    const float* Wp2    = (const float*)d_in[15];
    const float* bp2    = (const float*)d_in[16];
    float* out = (float*)d_out;

    float* f = (float*)d_ws;
    size_t o = 0;
    float*  XB    = f + o; o += (size_t)C_N * C_H;     // emb16 early; gcn1 X; later Xtmp fp16
    float*  HB    = f + o; o += (size_t)C_N * C_H;     // Hhf fp16 GEMM out
    ushort* XFh   = (ushort*)(f + o); o += (size_t)C_N * C_H / 2;
    ushort* XFl   = (ushort*)(f + o); o += (size_t)C_N * C_H / 2;
    float*  wbuf  = f + o; o += C_E;
    float*  degb  = f + o; o += C_N;                   // -> selfw (layer 1)
    int*    indegb= (int*)(f + o); o += C_N;           // adjacent: one memset
    float*  dinv  = f + o; o += C_N;
    int*    rowst = (int*)(f + o); o += C_N;
    int*    curs  = (int*)(f + o); o += C_N;
    int*    csrs  = (int*)(f + o); o += C_E;
    float*  csrn  = f + o; o += C_E;
    float*  deg1  = f + o; o += C_B * C_K1;            // selfw1
    int*    indeg1= (int*)(f + o); o += C_B * C_K1;
    int*    rowst1= (int*)(f + o); o += C_B * C_K1;
    float*  outb  = f + o; o += C_B * C_H;
    float*  scoreQ= f + o; o += 4 * (size_t)C_N;
    float*  invnp = f + o; o += 16;
    ushort* W0h   = (ushort*)(f + o); o += C_H * C_H / 2;
    ushort* W0l   = (ushort*)(f + o); o += C_H * C_H / 2;
    ushort* W1h   = (ushort*)(f + o); o += C_H * C_H / 2;
    ushort* W1l   = (ushort*)(f + o); o += C_H * C_H / 2;

    ushort* emb16 = (ushort*)XB;                       // dead before gcn_lds1 writes XB
    ushort* Hhf   = (ushort*)HB;
    ushort* Xtmp  = (ushort*)XB;                       // layer-2 X (fp16), after pool1

    hipMemsetAsync(degb, 0, 2 * C_N * sizeof(float), stream);

    k_pre<<<8812, 256, 0, stream>>>(emb, emb16, eattr, dst, wbuf, degb, indegb,
                                    W0, W1, W0h, W0l, W1h, W1l, p0, p1, invnp);
    k_st_scan<<<2048 + C_B, 256, 0, stream>>>(tokens, emb16, XFh, XFl,
                                              indegb, rowst, curs, degb, dinv);

    // ---- layer 1: GEMM (+ CSR build riding along) ----
    k_gemm1_csr<<<512 + C_E / 256, 256, 0, stream>>>(
        XFh, XFl, W0h, W0l, Hhf, src, dst, wbuf, dinv, curs, csrs, csrn);
    k_gcn_lds1<<<dim3(4, C_B), 512, 0, stream>>>(
        Hhf, rowst, indegb, csrs, csrn, degb, b0, p0, XB, scoreQ);

    k_pool1_fused<<<C_B, 512, 0, stream>>>(
        scoreQ, invnp, XB, src, dst, wbuf, wg, bg, XFh, XFl, outb,
        deg1, rowst1, indeg1, csrs, csrn);

    // ---- layer 2 ----
    k_gemm_mfma<<<dim3((C_B * C_K1) / 128, 2), 256, 0, stream>>>(XFh, XFl, W1h, W1l, Hhf);
    k_gcn_lds2<<<dim3(2, C_B), 512, 0, stream>>>(
        Hhf, rowst1, indeg1, csrs, csrn, deg1, b1, p1, Xtmp, scoreQ);

    k_pool2_head<<<C_B, C_K1, 0, stream>>>(
        scoreQ, invnp, Xtmp, wg, bg, outb, Wp1, bp1, Wp2, bp2, out);
}

// Round 10
// 351.333 us; speedup vs baseline: 1.3067x; 1.3067x over previous
//
#include <hip/hip_runtime.h>
#include <hip/hip_bf16.h>

constexpr int C_B   = 64;
constexpr int C_NPG = 512;
constexpr int C_N   = 32768;
constexpr int C_E   = 524288;
constexpr int C_L   = 16;
constexpr int C_H   = 256;
constexpr int C_P   = 128;
constexpr int C_K1  = 256;
constexpr int C_K2  = 128;
constexpr int C_V   = 50000;

typedef __attribute__((ext_vector_type(8)))  short  short8;
typedef __attribute__((ext_vector_type(16))) float  float16;
typedef unsigned short ushort;
typedef unsigned int   uint;

__device__ inline void split_bf16(float x, ushort& h, ushort& l) {
    __hip_bfloat16 bh = __float2bfloat16(x);
    float fh = __bfloat162float(bh);
    __hip_bfloat16 bl = __float2bfloat16(x - fh);
    h = __builtin_bit_cast(ushort, bh);
    l = __builtin_bit_cast(ushort, bl);
}

__device__ inline ushort f2h(float x) {
    return __builtin_bit_cast(ushort, (_Float16)x);
}
__device__ inline float h2f(ushort x) {
    return (float)__builtin_bit_cast(_Float16, x);
}
__device__ inline float4 h4_to_f4(ushort4 v) {
    return make_float4(h2f(v.x), h2f(v.y), h2f(v.z), h2f(v.w));
}

// hybrid bitonic sort, descending
template <int NPER>
__device__ inline void bitonic_desc(float& v, int& idx, float* svL, int* siL, int t) {
    #pragma unroll
    for (int k = 2; k <= NPER; k <<= 1) {
        bool desc = ((t & k) == 0);
        #pragma unroll
        for (int j = k >> 1; j > 0; j >>= 1) {
            bool amLo = ((t & j) == 0);
            bool keepMax = (desc == amLo);
            float pv; int pi;
            if (j >= 64) {
                __syncthreads();
                svL[t] = v; siL[t] = idx;
                __syncthreads();
                pv = svL[t ^ j]; pi = siL[t ^ j];
            } else {
                pv = __shfl_xor(v, j, 64);
                pi = __shfl_xor(idx, j, 64);
            }
            bool take = keepMax ? (pv > v) : (pv < v);
            if (take) { v = pv; idx = pi; }
        }
    }
}

// ---------------- fused preprocessing: embcvt | edge_w | wprep | p-norms -----
__global__ void k_pre(const float* __restrict__ emb, ushort* __restrict__ emb16,
                      const float* __restrict__ ea, const int* __restrict__ dst,
                      float* __restrict__ w, float* __restrict__ degb, int* __restrict__ indegb,
                      const float* __restrict__ W0, const float* __restrict__ W1,
                      ushort* __restrict__ W0h, ushort* __restrict__ W0l,
                      ushort* __restrict__ W1h, ushort* __restrict__ W1l,
                      const float* __restrict__ p0, const float* __restrict__ p1,
                      float* __restrict__ invnp) {
    int b = blockIdx.x, t = threadIdx.x;
    __shared__ float r[256];
    if (b < 6250) {
        int i = (b * 256 + t) * 8;
        float4 a = *(const float4*)&emb[i];
        float4 c = *(const float4*)&emb[i + 4];
        short8 o;
        o[0] = (short)f2h(a.x); o[1] = (short)f2h(a.y);
        o[2] = (short)f2h(a.z); o[3] = (short)f2h(a.w);
        o[4] = (short)f2h(c.x); o[5] = (short)f2h(c.y);
        o[6] = (short)f2h(c.z); o[7] = (short)f2h(c.w);
        *(short8*)&emb16[i] = o;
    } else if (b < 8298) {
        int e = (b - 6250) * 256 + t;
        float ww = 0.5f * (ea[2 * e] + ea[2 * e + 1]);
        w[e] = ww;
        int d = dst[e];
        atomicAdd(&degb[d], ww);
        atomicAdd(&indegb[d], 1);
    } else if (b < 8810) {
        int g = (b - 8298) * 256 + t;
        int which = g >> 16;
        int idx = g & 65535;
        int k = idx >> 8, n = idx & 255;
        float x = (which ? W1 : W0)[idx];
        ushort h, l;
        split_bf16(x, h, l);
        size_t a = ((size_t)(n >> 5) * 16 + (k >> 4)) * 512 + ((k >> 3) & 1) * 256
                 + (n & 31) * 8 + (k & 7);
        if (which) { W1h[a] = h; W1l[a] = l; }
        else       { W0h[a] = h; W0l[a] = l; }
    } else {
        const float* p = (b == 8810) ? p0 : p1;
        float v = p[t];
        r[t] = v * v; __syncthreads();
        for (int s = 128; s; s >>= 1) { if (t < s) r[t] += r[t + s]; __syncthreads(); }
        if (t == 0) invnp[b - 8810] = rsqrtf(r[0]);
    }
}

// ---------------- ST encoder (16 rows/block) + layer-1 scan (merged) ---------
__global__ __launch_bounds__(256)
void k_st_scan(const int* __restrict__ tokens, const ushort* __restrict__ emb16,
               ushort* __restrict__ Xh, ushort* __restrict__ Xl,
               const int* __restrict__ indeg, int* __restrict__ rowstart,
               int* __restrict__ cursor, float* __restrict__ deg,
               float* __restrict__ dinv) {
    __shared__ float Xs[16 * 257];
    __shared__ int tokS[256];
    int blk = blockIdx.x, t = threadIdx.x;
    if (blk < 2048) {                       // st_encode: 16 nodes per block
        tokS[t] = tokens[(size_t)blk * 256 + t];
        __syncthreads();
        int w = t >> 6, lane = t & 63;
        #pragma unroll
        for (int i = 0; i < 4; ++i) {
            int nl = w * 4 + i;
            float4 acc = make_float4(0.f, 0.f, 0.f, 0.f);
            int cnt = 0;
            #pragma unroll
            for (int tt = 0; tt < C_L; ++tt) {
                int tk = tokS[nl * 16 + tt];          // wave-uniform
                if (tk != 0) {
                    float4 ev = h4_to_f4(*(const ushort4*)&emb16[(size_t)tk * C_H + lane * 4]);
                    acc.x += ev.x; acc.y += ev.y; acc.z += ev.z; acc.w += ev.w;
                    cnt++;
                }
            }
            float inv = 1.f / fmaxf((float)cnt, 1.f);
            float* xr = &Xs[nl * 257 + lane * 4];
            xr[0] = acc.x * inv; xr[1] = acc.y * inv;
            xr[2] = acc.z * inv; xr[3] = acc.w * inv;
        }
        __syncthreads();
        int mtile = blk >> 1, rlo = (blk & 1) * 16;
        #pragma unroll
        for (int i = 0; i < 2; ++i) {
            int u = t + 256 * i;                      // [0,512)
            int kst = u >> 5, rr = u & 15, khalf = (u >> 4) & 1;
            int kb = kst * 16 + khalf * 8;
            int ln = khalf * 32 + rlo + rr;
            short8 hv, lv;
            #pragma unroll
            for (int j = 0; j < 8; ++j) {
                ushort h, l;
                split_bf16(Xs[rr * 257 + kb + j], h, l);
                hv[j] = (short)h; lv[j] = (short)l;
            }
            size_t base = (size_t)mtile * 8192 + ((size_t)kst * 64 + ln) * 8;
            *(short8*)&Xh[base] = hv;
            *(short8*)&Xl[base] = lv;
        }
    } else {                                // scan: one wave per graph
        int g = blk - 2048;
        if (t < 64) {
            int lane = t;
            int nodebase = g * C_NPG + lane * 8;
            int a[8];
            int tot = 0;
            #pragma unroll
            for (int i = 0; i < 8; ++i) { a[i] = indeg[nodebase + i]; tot += a[i]; }
            int sc = tot;
            #pragma unroll
            for (int off = 1; off < 64; off <<= 1) {
                int pv = __shfl_up(sc, off, 64);
                if (lane >= off) sc += pv;
            }
            int run = g * 8192 + sc - tot;
            #pragma unroll
            for (int i = 0; i < 8; ++i) {
                rowstart[nodebase + i] = run;
                cursor[nodebase + i]   = run;
                run += a[i];
                float d = deg[nodebase + i] + 1.f;
                dinv[nodebase + i] = rsqrtf(d);
                deg[nodebase + i]  = 1.f / d;         // selfw
            }
        }
    }
}

// ---------------- GEMM body (split-bf16 3-term MFMA, fp16 out) ---------------
__device__ inline void gemm_body(const ushort* __restrict__ Ah, const ushort* __restrict__ Al,
                                 const ushort* __restrict__ Bh, const ushort* __restrict__ Bl,
                                 ushort* __restrict__ C, int mb, int nb, int tid) {
    __shared__ short lds[16384];
    int lane = tid & 63;
    int wid  = tid >> 6;
    int wm   = wid & 1, wn = wid >> 1;
    float16 acc[2][2];
    #pragma unroll
    for (int mi = 0; mi < 2; ++mi)
        #pragma unroll
        for (int ni = 0; ni < 2; ++ni)
            #pragma unroll
            for (int r = 0; r < 16; ++r) acc[mi][ni][r] = 0.f;
    for (int kc = 0; kc < 8; ++kc) {
        __syncthreads();
        #pragma unroll
        for (int i = 0; i < 4; ++i) {
            int a  = tid + 256 * i;
            int s  = a >> 9;
            int mt = (a >> 7) & 3;
            int k2 = (a >> 6) & 1;
            int ln = a & 63;
            const ushort* ap = (s ? Al : Ah)
                + (((size_t)(mb * 4 + mt) * 16 + kc * 2 + k2) * 64 + ln) * 8;
            *(int4*)&lds[a * 8] = *(const int4*)ap;
            const ushort* bp = (s ? Bl : Bh)
                + (((size_t)(nb * 4 + mt) * 16 + kc * 2 + k2) * 64 + ln) * 8;
            *(int4*)&lds[8192 + a * 8] = *(const int4*)bp;
        }
        __syncthreads();
        #pragma unroll
        for (int k2 = 0; k2 < 2; ++k2) {
            short8 ah[2], al[2], bh[2], bl[2];
            #pragma unroll
            for (int mi = 0; mi < 2; ++mi) {
                int mt = wm * 2 + mi;
                ah[mi] = *(short8*)&lds[((mt * 2 + k2) * 64 + lane) * 8];
                al[mi] = *(short8*)&lds[(((4 + mt) * 2 + k2) * 64 + lane) * 8];
            }
            #pragma unroll
            for (int ni = 0; ni < 2; ++ni) {
                int nt = wn * 2 + ni;
                bh[ni] = *(short8*)&lds[8192 + ((nt * 2 + k2) * 64 + lane) * 8];
                bl[ni] = *(short8*)&lds[8192 + (((4 + nt) * 2 + k2) * 64 + lane) * 8];
            }
            #pragma unroll
            for (int mi = 0; mi < 2; ++mi)
                #pragma unroll
                for (int ni = 0; ni < 2; ++ni) {
                    acc[mi][ni] = __builtin_amdgcn_mfma_f32_32x32x16_bf16(
                        ah[mi], bh[ni], acc[mi][ni], 0, 0, 0);
                    acc[mi][ni] = __builtin_amdgcn_mfma_f32_32x32x16_bf16(
                        ah[mi], bl[ni], acc[mi][ni], 0, 0, 0);
                    acc[mi][ni] = __builtin_amdgcn_mfma_f32_32x32x16_bf16(
                        al[mi], bh[ni], acc[mi][ni], 0, 0, 0);
                }
        }
    }
    int col = lane & 31;
    int rquad = 4 * (lane >> 5);
    #pragma unroll
    for (int mi = 0; mi < 2; ++mi)
        #pragma unroll
        for (int ni = 0; ni < 2; ++ni) {
            int mbase = mb * 128 + wm * 64 + mi * 32;
            int nbase = nb * 128 + wn * 64 + ni * 32 + col;
            #pragma unroll
            for (int r = 0; r < 16; ++r) {
                int row = (r & 3) + 8 * (r >> 2) + rquad;
                C[(size_t)(mbase + row) * C_H + nbase] = f2h(acc[mi][ni][r]);
            }
        }
}

// ---------------- GEMM-1 + layer-1 CSR build (merged launch) -----------------
__global__ __launch_bounds__(256)
void k_gemm1_csr(const ushort* __restrict__ Ah, const ushort* __restrict__ Al,
                 const ushort* __restrict__ Bh, const ushort* __restrict__ Bl,
                 ushort* __restrict__ C,
                 const int* __restrict__ src, const int* __restrict__ dst,
                 const float* __restrict__ wv, const float* __restrict__ dinv,
                 int* __restrict__ cursor, int* __restrict__ csr_src,
                 float* __restrict__ csr_nrm) {
    int b = blockIdx.x, t = threadIdx.x;
    if (b < 512) {
        gemm_body(Ah, Al, Bh, Bl, C, b & 255, b >> 8, t);
    } else {
        int e = (b - 512) * 256 + t;
        int s = src[e], d = dst[e];
        int slot = atomicAdd(&cursor[d], 1);
        csr_src[slot] = s;
        csr_nrm[slot] = dinv[s] * wv[e] * dinv[d];
    }
}

// ---------------- GEMM-2 (standalone) ----------------
__global__ __launch_bounds__(256)
void k_gemm_mfma(const ushort* __restrict__ Ah, const ushort* __restrict__ Al,
                 const ushort* __restrict__ Bh, const ushort* __restrict__ Bl,
                 ushort* __restrict__ C) {
    gemm_body(Ah, Al, Bh, Bl, C, blockIdx.x, blockIdx.y, threadIdx.x);
}

// ---------------- GCN aggregate: wave per node, fp32 out + score (layer 1) ---
__global__ __launch_bounds__(256)
void k_gcn_gather1(const ushort* __restrict__ Hm, const int* __restrict__ rowstart,
                   const int* __restrict__ indeg, const int* __restrict__ csr_src,
                   const float* __restrict__ csr_nrm, const float* __restrict__ selfw,
                   const float* __restrict__ bias, const float* __restrict__ p,
                   const float* __restrict__ invnp, float* __restrict__ Xout,
                   float* __restrict__ score, int nnodes) {
    int n    = (blockIdx.x * blockDim.x + threadIdx.x) >> 6;
    int lane = threadIdx.x & 63;
    if (n >= nnodes) return;
    int h4 = lane * 4;
    float4 hv = h4_to_f4(*(const ushort4*)&Hm[(size_t)n * C_H + h4]);
    float  sw = selfw[n];
    float4 bv = *(const float4*)&bias[h4];
    float4 acc = make_float4(fmaf(hv.x, sw, bv.x), fmaf(hv.y, sw, bv.y),
                             fmaf(hv.z, sw, bv.z), fmaf(hv.w, sw, bv.w));
    int start = rowstart[n], cnt = indeg[n];
    const int*   sp = csr_src + start;
    const float* np = csr_nrm + start;
    #pragma unroll 4
    for (int j = 0; j < cnt; ++j) {
        int   s  = sp[j];
        float nm = np[j];
        float4 xv = h4_to_f4(*(const ushort4*)&Hm[(size_t)s * C_H + h4]);
        acc.x = fmaf(nm, xv.x, acc.x);
        acc.y = fmaf(nm, xv.y, acc.y);
        acc.z = fmaf(nm, xv.z, acc.z);
        acc.w = fmaf(nm, xv.w, acc.w);
    }
    acc.x = fmaxf(acc.x, 0.f); acc.y = fmaxf(acc.y, 0.f);
    acc.z = fmaxf(acc.z, 0.f); acc.w = fmaxf(acc.w, 0.f);
    *(float4*)&Xout[(size_t)n * C_H + h4] = acc;
    float4 pv = *(const float4*)&p[h4];
    float s = acc.x * pv.x + acc.y * pv.y + acc.z * pv.z + acc.w * pv.w;
    #pragma unroll
    for (int m = 32; m; m >>= 1) s += __shfl_xor(s, m, 64);
    if (lane == 0) score[n] = s * invnp[0];
}

// ---------------- GCN aggregate: wave per node, fp16 out + score (layer 2) ---
__global__ __launch_bounds__(256)
void k_gcn_gather2(const ushort* __restrict__ Hm, const int* __restrict__ rowstart,
                   const int* __restrict__ indeg, const int* __restrict__ csr_src,
                   const float* __restrict__ csr_nrm, const float* __restrict__ selfw,
                   const float* __restrict__ bias, const float* __restrict__ p,
                   const float* __restrict__ invnp, ushort* __restrict__ Xout,
                   float* __restrict__ score, int nnodes) {
    int n    = (blockIdx.x * blockDim.x + threadIdx.x) >> 6;
    int lane = threadIdx.x & 63;
    if (n >= nnodes) return;
    int h4 = lane * 4;
    float4 hv = h4_to_f4(*(const ushort4*)&Hm[(size_t)n * C_H + h4]);
    float  sw = selfw[n];
    float4 bv = *(const float4*)&bias[h4];
    float4 acc = make_float4(fmaf(hv.x, sw, bv.x), fmaf(hv.y, sw, bv.y),
                             fmaf(hv.z, sw, bv.z), fmaf(hv.w, sw, bv.w));
    int start = rowstart[n], cnt = indeg[n];
    const int*   sp = csr_src + start;
    const float* np = csr_nrm + start;
    #pragma unroll 4
    for (int j = 0; j < cnt; ++j) {
        int   s  = sp[j];
        float nm = np[j];
        float4 xv = h4_to_f4(*(const ushort4*)&Hm[(size_t)s * C_H + h4]);
        acc.x = fmaf(nm, xv.x, acc.x);
        acc.y = fmaf(nm, xv.y, acc.y);
        acc.z = fmaf(nm, xv.z, acc.z);
        acc.w = fmaf(nm, xv.w, acc.w);
    }
    acc.x = fmaxf(acc.x, 0.f); acc.y = fmaxf(acc.y, 0.f);
    acc.z = fmaxf(acc.z, 0.f); acc.w = fmaxf(acc.w, 0.f);
    ushort4 o;
    o.x = f2h(acc.x); o.y = f2h(acc.y); o.z = f2h(acc.z); o.w = f2h(acc.w);
    *(ushort4*)&Xout[(size_t)n * C_H + h4] = o;
    float4 pv = *(const float4*)&p[h4];
    float s = acc.x * pv.x + acc.y * pv.y + acc.z * pv.z + acc.w * pv.w;
    #pragma unroll
    for (int m = 32; m; m >>= 1) s += __shfl_xor(s, m, 64);
    if (lane == 0) score[n] = s * invnp[0];
}

// ---------------- fused pool-1: sort + attpool-1 + frag emit + layer-2 prep --
__global__ __launch_bounds__(512)
void k_pool1_fused(const float* __restrict__ score, const float* __restrict__ X,
                   const int* __restrict__ src, const int* __restrict__ dst,
                   const float* __restrict__ wbuf,
                   const float* __restrict__ wg, const float* __restrict__ bg,
                   ushort* __restrict__ XFh, ushort* __restrict__ XFl,
                   float* __restrict__ outb,
                   float* __restrict__ selfw1, int* __restrict__ rowst1,
                   int* __restrict__ indeg1, int* __restrict__ csrs,
                   float* __restrict__ csrn) {
    int g = blockIdx.x, t = threadIdx.x;
    int lane = t & 63, w = t >> 6;
    __shared__ float svL[C_NPG];
    __shared__ int   siL[C_NPG];
    __shared__ int   nooL[C_NPG];
    __shared__ int   olds[C_K1];
    __shared__ float gt[C_K1];
    __shared__ float sd[C_K1];
    __shared__ float red[C_K1];
    __shared__ float an[C_K1];
    __shared__ float wsum[8][C_H];
    __shared__ int   indegL[C_K1];
    __shared__ float degL[C_K1];
    __shared__ float dinvL[C_K1];
    __shared__ int   cursL[C_K1];

    float v = score[g * C_NPG + t];
    int idx = t;
    bitonic_desc<C_NPG>(v, idx, svL, siL, t);
    __syncthreads();
    nooL[idx] = (t < C_K1) ? t : -1;
    if (t < C_K1) {
        olds[t]   = idx;
        gt[t]     = tanhf(v);
        indegL[t] = 0;
        degL[t]   = 0.f;
    }
    __syncthreads();

    float bgv = bg[0];
    {
        int r = t >> 1, half = t & 1;
        const float* xr = &X[(size_t)(g * C_NPG + olds[r]) * C_H + half * 128];
        const float* wr = &wg[half * 128];
        float s = 0.f;
        #pragma unroll
        for (int kk = 0; kk < 128; kk += 4) {
            float4 xv = *(const float4*)&xr[kk];
            float4 wv = *(const float4*)&wr[kk];
            s += xv.x * wv.x + xv.y * wv.y + xv.z * wv.z + xv.w * wv.w;
        }
        if (half) red[r] = s;
        __syncthreads();
        if (!half) sd[r] = gt[r] * (s + red[r]) + bgv;
        __syncthreads();
    }
    if (w == 0) {
        float m = fmaxf(fmaxf(sd[lane], sd[lane + 64]), fmaxf(sd[lane + 128], sd[lane + 192]));
        #pragma unroll
        for (int mm = 32; mm; mm >>= 1) m = fmaxf(m, __shfl_xor(m, mm, 64));
        if (lane == 0) red[0] = m;
    }
    __syncthreads();
    float mx = red[0];
    if (t < C_K1) an[t] = expf(sd[t] - mx);
    __syncthreads();
    if (w == 0) {
        float s4 = an[lane] + an[lane + 64] + an[lane + 128] + an[lane + 192];
        #pragma unroll
        for (int mm = 32; mm; mm >>= 1) s4 += __shfl_xor(s4, mm, 64);
        if (lane == 0) red[1] = s4;
    }
    __syncthreads();
    if (t < C_K1) an[t] = an[t] / red[1] * gt[t];
    __syncthreads();
    {
        float4 a4 = make_float4(0.f, 0.f, 0.f, 0.f);
        #pragma unroll 4
        for (int r = 0; r < 32; ++r) {
            int rr = w * 32 + r;
            float a = an[rr];
            float4 xv = *(const float4*)&X[(size_t)(g * C_NPG + olds[rr]) * C_H + lane * 4];
            a4.x = fmaf(a, xv.x, a4.x); a4.y = fmaf(a, xv.y, a4.y);
            a4.z = fmaf(a, xv.z, a4.z); a4.w = fmaf(a, xv.w, a4.w);
        }
        *(float4*)&wsum[w][lane * 4] = a4;
        __syncthreads();
        if (t < C_H) {
            float s = wsum[0][t] + wsum[1][t] + wsum[2][t] + wsum[3][t]
                    + wsum[4][t] + wsum[5][t] + wsum[6][t] + wsum[7][t];
            outb[g * C_H + t] = s;
        }
    }

    // frag emission for GEMM-2 directly from global X
    #pragma unroll
    for (int i = 0; i < 16; ++i) {
        int u   = t + 512 * i;
        int mt  = u >> 10;
        int c   = u & 1023;
        int kst = c >> 6, ln = c & 63, ml = ln & 31;
        int kb  = kst * 16 + (ln >> 5) * 8;
        int r   = mt * 32 + ml;
        const float* xp = &X[(size_t)(g * C_NPG + olds[r]) * C_H + kb];
        float gg = gt[r];
        float4 a = *(const float4*)&xp[0];
        float4 b = *(const float4*)&xp[4];
        float e8[8] = {a.x * gg, a.y * gg, a.z * gg, a.w * gg,
                       b.x * gg, b.y * gg, b.z * gg, b.w * gg};
        short8 hv, lv;
        #pragma unroll
        for (int j = 0; j < 8; ++j) {
            ushort h, l;
            split_bf16(e8[j], h, l);
            hv[j] = (short)h; lv[j] = (short)l;
        }
        size_t base = (size_t)(g * 8 + mt) * 8192 + (size_t)c * 8;
        *(short8*)&XFh[base] = hv;
        *(short8*)&XFl[base] = lv;
    }

    // layer-2 graph prep
    int   nsR[16], ndR[16];
    float wwR[16];
    #pragma unroll
    for (int i = 0; i < 16; ++i) {
        int e  = g * 8192 + t + 512 * i;
        int ns = nooL[src[e] - g * C_NPG];
        int nd = nooL[dst[e] - g * C_NPG];
        float ww = wbuf[e];
        nsR[i] = ns; ndR[i] = nd; wwR[i] = ww;
        if (ns >= 0 && nd >= 0) {
            atomicAdd(&indegL[nd], 1);
            unsafeAtomicAdd(&degL[nd], ww);
        }
    }
    __syncthreads();
    if (t < C_K1) {
        float d = degL[t] + 1.f;
        dinvL[t] = rsqrtf(d);
        selfw1[g * C_K1 + t] = 1.f / d;
        indeg1[g * C_K1 + t] = indegL[t];
    }
    if (w == 0) {
        int a0 = indegL[lane * 4], a1 = indegL[lane * 4 + 1];
        int a2 = indegL[lane * 4 + 2], a3 = indegL[lane * 4 + 3];
        int s4 = a0 + a1 + a2 + a3;
        int sc = s4;
        #pragma unroll
        for (int off = 1; off < 64; off <<= 1) {
            int pv = __shfl_up(sc, off, 64);
            if (lane >= off) sc += pv;
        }
        int base = g * 8192 + (sc - s4);
        cursL[lane * 4]     = base;
        cursL[lane * 4 + 1] = base + a0;
        cursL[lane * 4 + 2] = base + a0 + a1;
        cursL[lane * 4 + 3] = base + a0 + a1 + a2;
        rowst1[g * C_K1 + lane * 4]     = base;
        rowst1[g * C_K1 + lane * 4 + 1] = base + a0;
        rowst1[g * C_K1 + lane * 4 + 2] = base + a0 + a1;
        rowst1[g * C_K1 + lane * 4 + 3] = base + a0 + a1 + a2;
    }
    __syncthreads();
    #pragma unroll
    for (int i = 0; i < 16; ++i) {
        int ns = nsR[i], nd = ndR[i];
        if (ns >= 0 && nd >= 0) {
            int slot = atomicAdd(&cursL[nd], 1);
            csrs[slot] = g * C_K1 + ns;
            csrn[slot] = dinvL[ns] * wwR[i] * dinvL[nd];
        }
    }
}

// ---------------- fused pool-2 + attpool-2 + projection head -----------------
__global__ __launch_bounds__(256)
void k_pool2_head(const float* __restrict__ score, const ushort* __restrict__ Xtmp,
                  const float* __restrict__ wg, const float* __restrict__ bg,
                  const float* __restrict__ outb,
                  const float* __restrict__ Wp1, const float* __restrict__ bp1,
                  const float* __restrict__ Wp2, const float* __restrict__ bp2,
                  float* __restrict__ dout) {
    int g = blockIdx.x, t = threadIdx.x;
    int lane = t & 63, w = t >> 6;
    __shared__ float svL[C_K1];
    __shared__ int   siL[C_K1];
    __shared__ int   olds[C_K2];
    __shared__ float gt[C_K2];
    __shared__ float sd[C_K2];
    __shared__ float red2[C_K2];
    __shared__ float an[C_K2];
    __shared__ float wsum[4][C_H];
    __shared__ float so[C_H];

    float v = score[g * C_K1 + t];
    int idx = t;
    bitonic_desc<C_K1>(v, idx, svL, siL, t);
    __syncthreads();
    if (t < C_K2) { olds[t] = idx; gt[t] = tanhf(v); }
    __syncthreads();

    float bgv = bg[0];
    {
        int r = t >> 1, half = t & 1;
        const ushort* xr = &Xtmp[(size_t)(g * C_K1 + olds[r]) * C_H + half * 128];
        const float* wr = &wg[half * 128];
        float s = 0.f;
        #pragma unroll
        for (int kk = 0; kk < 128; kk += 4) {
            float4 xv = h4_to_f4(*(const ushort4*)&xr[kk]);
            float4 wv = *(const float4*)&wr[kk];
            s += xv.x * wv.x + xv.y * wv.y + xv.z * wv.z + xv.w * wv.w;
        }
        if (half) red2[r] = s;
        __syncthreads();
        if (!half) sd[r] = gt[r] * (s + red2[r]) + bgv;
        __syncthreads();
    }
    if (w == 0) {
        float m = fmaxf(sd[lane], sd[lane + 64]);
        #pragma unroll
        for (int mm = 32; mm; mm >>= 1) m = fmaxf(m, __shfl_xor(m, mm, 64));
        if (lane == 0) red2[0] = m;
    }
    __syncthreads();
    float mx = red2[0];
    if (t < C_K2) an[t] = expf(sd[t] - mx);
    __syncthreads();
    if (w == 0) {
        float s2 = an[lane] + an[lane + 64];
        #pragma unroll
        for (int mm = 32; mm; mm >>= 1) s2 += __shfl_xor(s2, mm, 64);
        if (lane == 0) red2[1] = s2;
    }
    __syncthreads();
    if (t < C_K2) an[t] = an[t] / red2[1] * gt[t];
    __syncthreads();
    {
        float4 a4 = make_float4(0.f, 0.f, 0.f, 0.f);
        #pragma unroll 4
        for (int r = 0; r < 32; ++r) {
            int rr = w * 32 + r;
            float a = an[rr];
            float4 xv = h4_to_f4(*(const ushort4*)&Xtmp[(size_t)(g * C_K1 + olds[rr]) * C_H + lane * 4]);
            a4.x = fmaf(a, xv.x, a4.x); a4.y = fmaf(a, xv.y, a4.y);
            a4.z = fmaf(a, xv.z, a4.z); a4.w = fmaf(a, xv.w, a4.w);
        }
        *(float4*)&wsum[w][lane * 4] = a4;
    }
    __syncthreads();
    float o = outb[g * C_H + t] + wsum[0][t] + wsum[1][t] + wsum[2][t] + wsum[3][t];
    so[t] = o;
    dout[C_B * C_P + g * C_H + t] = o;      // second output
    __syncthreads();

    // projection head
    float lg = 0.f;
    if (t < C_P) {
        float acc = bp1[t];
        for (int k = 0; k < C_H; ++k) acc += so[k] * Wp1[k * C_P + t];
        float hv = fmaxf(acc, 0.f);
        an[t] = hv;                          // reuse as sh
    }
    __syncthreads();
    if (t < C_P) {
        lg = bp2[t];
        for (int k = 0; k < C_P; ++k) lg += an[k] * Wp2[k * C_P + t];
        red2[t] = lg * lg;
    }
    __syncthreads();
    for (int s = 64; s; s >>= 1) { if (t < s) red2[t] += red2[t + s]; __syncthreads(); }
    float nrm = fmaxf(sqrtf(red2[0]), 1e-12f);
    if (t < C_P) dout[g * C_P + t] = lg / nrm;
}

extern "C" void kernel_launch(void* const* d_in, const int* in_sizes, int n_in,
                              void* d_out, int out_size, void* d_ws, size_t ws_size,
                              hipStream_t stream) {
    const int*   tokens = (const int*)d_in[0];
    const int*   src    = (const int*)d_in[1];
    const int*   dst    = (const int*)d_in[2];
    const float* eattr  = (const float*)d_in[3];
    const float* emb    = (const float*)d_in[4];
    const float* W0     = (const float*)d_in[5];
    const float* b0     = (const float*)d_in[6];
    const float* W1     = (const float*)d_in[7];
    const float* b1     = (const float*)d_in[8];
    const float* p0     = (const float*)d_in[9];
    const float* p1     = (const float*)d_in[10];
    const float* wg     = (const float*)d_in[11];
    const float* bg     = (const float*)d_in[12];
    const float* Wp1    = (const float*)d_in[13];
    const float* bp1    = (const float*)d_in[14];
    const float* Wp2    = (const float*)d_in[15];
    const float* bp2    = (const float*)d_in[16];
    float* out = (float*)d_out;

    float* f = (float*)d_ws;
    size_t o = 0;
    float*  XB    = f + o; o += (size_t)C_N * C_H;     // emb16 early; gcn1 X fp32; later Xtmp fp16
    float*  HB    = f + o; o += (size_t)C_N * C_H;     // Hhf fp16 GEMM out
    ushort* XFh   = (ushort*)(f + o); o += (size_t)C_N * C_H / 2;
    ushort* XFl   = (ushort*)(f + o); o += (size_t)C_N * C_H / 2;
    float*  wbuf  = f + o; o += C_E;
    float*  degb  = f + o; o += C_N;                   // -> selfw (layer 1)
    int*    indegb= (int*)(f + o); o += C_N;           // adjacent: one memset
    float*  dinv  = f + o; o += C_N;
    int*    rowst = (int*)(f + o); o += C_N;
    int*    curs  = (int*)(f + o); o += C_N;
    int*    csrs  = (int*)(f + o); o += C_E;
    float*  csrn  = f + o; o += C_E;
    float*  deg1  = f + o; o += C_B * C_K1;            // selfw1
    int*    indeg1= (int*)(f + o); o += C_B * C_K1;
    int*    rowst1= (int*)(f + o); o += C_B * C_K1;
    float*  outb  = f + o; o += C_B * C_H;
    float*  score = f + o; o += C_N;
    float*  invnp = f + o; o += 16;
    ushort* W0h   = (ushort*)(f + o); o += C_H * C_H / 2;
    ushort* W0l   = (ushort*)(f + o); o += C_H * C_H / 2;
    ushort* W1h   = (ushort*)(f + o); o += C_H * C_H / 2;
    ushort* W1l   = (ushort*)(f + o); o += C_H * C_H / 2;

    ushort* emb16 = (ushort*)XB;                       // dead before gcn_gather1 writes XB
    ushort* Hhf   = (ushort*)HB;
    ushort* Xtmp  = (ushort*)XB;                       // layer-2 X (fp16), after pool1

    hipMemsetAsync(degb, 0, 2 * C_N * sizeof(float), stream);

    k_pre<<<8812, 256, 0, stream>>>(emb, emb16, eattr, dst, wbuf, degb, indegb,
                                    W0, W1, W0h, W0l, W1h, W1l, p0, p1, invnp);
    k_st_scan<<<2048 + C_B, 256, 0, stream>>>(tokens, emb16, XFh, XFl,
                                              indegb, rowst, curs, degb, dinv);

    // ---- layer 1: GEMM (+ CSR build riding along) ----
    k_gemm1_csr<<<512 + C_E / 256, 256, 0, stream>>>(
        XFh, XFl, W0h, W0l, Hhf, src, dst, wbuf, dinv, curs, csrs, csrn);
    k_gcn_gather1<<<(C_N * 64) / 256, 256, 0, stream>>>(
        Hhf, rowst, indegb, csrs, csrn, degb, b0, p0, invnp, XB, score, C_N);

    k_pool1_fused<<<C_B, 512, 0, stream>>>(
        score, XB, src, dst, wbuf, wg, bg, XFh, XFl, outb,
        deg1, rowst1, indeg1, csrs, csrn);

    // ---- layer 2 ----
    k_gemm_mfma<<<dim3((C_B * C_K1) / 128, 2), 256, 0, stream>>>(XFh, XFl, W1h, W1l, Hhf);
    k_gcn_gather2<<<(C_B * C_K1 * 64) / 256, 256, 0, stream>>>(
        Hhf, rowst1, indeg1, csrs, csrn, deg1, b1, p1, invnp + 1, Xtmp, score, C_B * C_K1);

    k_pool2_head<<<C_B, C_K1, 0, stream>>>(
        score, Xtmp, wg, bg, outb, Wp1, bp1, Wp2, bp2, out);
}